// Round 3
// baseline (359.408 us; speedup 1.0000x reference)
//
#include <hip/hip_runtime.h>
#include <stdint.h>

// ---------------------------------------------------------------------------
// KDGQA: x -> (Q,K,V) proj -> dynamic KV allocation from ||K||_F -> grouped
// attention -> output proj + bias.  B=8, P=1024, DIM=1024, H=16, KV=8, HD=64.
// R11: occupancy attack.  R8/R9/R10 all land at 64us with every intra-block
// schedule variant -> limiter is grid shape: 1024 blocks = 4 blk/CU = 50%
// occupancy cap (33% measured), ~2.6 waves/SIMD can't hide L2 latency.
// Now: 64 queries/block -> 2048 blocks; single-buffered LDS (Ks 8KB +
// Vt 9.2KB = 17.4KB) -> 9 blk/CU by LDS; __launch_bounds__(256,8) keeps
// VGPR<=64 -> 8 waves/SIMD -> 8 blk/CU resident = 100% theoretical occupancy.
// The 2-barrier/tile gll drain returns, but 8 co-resident blocks at different
// phases hide it via TLP (the m97-GEMM mechanism).  K/V gll + V-pack work
// doubles -- L2-served (~13 TB/s << 34.5 TB/s ceiling), a deliberate trade.
// GEMMs: XCD swizzle reverted (operands are L2/L3-resident; swizzle is a net
// cost in that regime).  setprio kept around attn MFMA clusters.
// ---------------------------------------------------------------------------

typedef float f32x4 __attribute__((ext_vector_type(4)));
typedef int   i32x2 __attribute__((ext_vector_type(2)));
typedef short s16x8 __attribute__((ext_vector_type(8)));
typedef short s16x4 __attribute__((ext_vector_type(4)));
typedef int   i32x4 __attribute__((ext_vector_type(4)));

__device__ __forceinline__ unsigned short f2bf(float f) {
  unsigned int u = __builtin_bit_cast(unsigned int, f);
  u = (u + 0x7FFFu + ((u >> 16) & 1u)) >> 16;   // round-to-nearest-even
  return (unsigned short)u;
}

// packed fp32x2 -> bf16x2 (low = a, high = b)
__device__ __forceinline__ unsigned int pk_bf16(float a, float b) {
#if __has_builtin(__builtin_amdgcn_cvt_pk_bf16_f32)
  auto v = __builtin_amdgcn_cvt_pk_bf16_f32(a, b);
  return __builtin_bit_cast(unsigned int, v);
#else
  unsigned int ua = __builtin_bit_cast(unsigned int, a);
  unsigned int ub = __builtin_bit_cast(unsigned int, b);
  ua += 0x7FFFu + ((ua >> 16) & 1u);
  ub += 0x7FFFu + ((ub >> 16) & 1u);
#if __has_builtin(__builtin_amdgcn_perm)
  return __builtin_amdgcn_perm(ub, ua, 0x07060302);
#else
  return (ua >> 16) | (ub & 0xFFFF0000u);
#endif
#endif
}

__device__ __forceinline__ float fast_exp2(float x) {
#if __has_builtin(__builtin_amdgcn_exp2f)
  return __builtin_amdgcn_exp2f(x);
#else
  return exp2f(x);
#endif
}

#if __has_builtin(__builtin_amdgcn_global_load_lds)
#define HAVE_GLL 1
typedef const __attribute__((address_space(1))) void* gas_ptr;
typedef __attribute__((address_space(3))) void* las_ptr;
__device__ __forceinline__ void gll16(const void* g, void* l) {
  __builtin_amdgcn_global_load_lds((gas_ptr)g, (las_ptr)l, 16, 0, 0);
}
#endif

// ---------------------------------------------------------------------------
// 1. fp32 -> bf16 conversion. Wq gets 0.125 (HD^-0.5) * log2(e) folded in so
//    attention softmax is a raw exp2.  Block 0 also zeroes the sumsq cells.
// ---------------------------------------------------------------------------
__global__ void convert_kernel(const float* __restrict__ x, const float* __restrict__ Wq,
                               const float* __restrict__ Wk, const float* __restrict__ Wv,
                               const float* __restrict__ Wp,
                               unsigned short* __restrict__ xb,
                               unsigned short* __restrict__ wqkv,
                               unsigned short* __restrict__ wpb,
                               float* __restrict__ sums) {
  if (blockIdx.x == 0 && threadIdx.x < 64) sums[threadIdx.x] = 0.0f;
  const long i = ((long)blockIdx.x * 256 + threadIdx.x) * 4;
  const float* src; unsigned short* dst; long off; float scale = 1.0f;
  if (i < 8388608L)       { src = x;  dst = xb;             off = i;             }
  else if (i < 9437184L)  { src = Wq; dst = wqkv;           off = i - 8388608L;  scale = 0.18033688011112042f; }
  else if (i < 9961472L)  { src = Wk; dst = wqkv + 1048576; off = i - 9437184L;  }
  else if (i < 10485760L) { src = Wv; dst = wqkv + 1572864; off = i - 9961472L;  }
  else                    { src = Wp; dst = wpb;            off = i - 10485760L; }
  f32x4 v = *(const f32x4*)(src + off);
  s16x4 o;
  o[0] = (short)f2bf(v[0] * scale);
  o[1] = (short)f2bf(v[1] * scale);
  o[2] = (short)f2bf(v[2] * scale);
  o[3] = (short)f2bf(v[3] * scale);
  *(s16x4*)(dst + off) = o;
}

// ---------------------------------------------------------------------------
// 2. GEMM  C[M][N] = A[M][1024] * B[N][1024]^T, 128x128 tile, BK=64, m97-style
//    global_load_lds staging with XOR chunk swizzle.  DO_SUMSQ: K-range blocks
//    reduce sum(acc^2) per (b, kv head) into sums[] via one atomic per wave.
// ---------------------------------------------------------------------------
template<int N, bool OUT_BF16, bool DO_SUMSQ>
__global__ __launch_bounds__(256)
void gemm_bt(const unsigned short* __restrict__ A,
             const unsigned short* __restrict__ Bw,
             unsigned short* __restrict__ Cb,
             float* __restrict__ Cf,
             const float* __restrict__ bias,
             float* __restrict__ sums) {
  __shared__ __align__(16) unsigned short As[8192];   // 128 rows x 64 shorts
  __shared__ __align__(16) unsigned short Bs[8192];
  constexpr int NB = N / 128;
  const int bm = blockIdx.x / NB, bn = blockIdx.x % NB;
  const int m0 = bm * 128, n0 = bn * 128;
  const int t = threadIdx.x;
  const int w = t >> 6, lane = t & 63, quad = lane >> 4, ln = lane & 15;
  const int wm = w & 1, wn = w >> 1;

  const int lrow = lane >> 3;                       // 0..7
  const int lc8  = ((lane & 7) ^ lrow) << 3;        // logical chunk offset (shorts)
  const unsigned short* agl = A  + (m0 + w * 32 + lrow) * 1024 + lc8;
  const unsigned short* bgl = Bw + (n0 + w * 32 + lrow) * 1024 + lc8;

  f32x4 acc[4][4] = {};

  for (int k0 = 0; k0 < 1024; k0 += 64) {
    __syncthreads();
#ifdef HAVE_GLL
    #pragma unroll
    for (int c = 0; c < 4; ++c) {
      gll16(agl + k0 + c * 8192, &As[w * 2048 + c * 512]);
      gll16(bgl + k0 + c * 8192, &Bs[w * 2048 + c * 512]);
    }
#else
    i32x4 ra[4], rb[4];
    #pragma unroll
    for (int c = 0; c < 4; ++c) {
      ra[c] = *(const i32x4*)(agl + k0 + c * 8192);
      rb[c] = *(const i32x4*)(bgl + k0 + c * 8192);
    }
    #pragma unroll
    for (int c = 0; c < 4; ++c) {
      *(i32x4*)(&As[w * 2048 + c * 512 + lane * 8]) = ra[c];
      *(i32x4*)(&Bs[w * 2048 + c * 512 + lane * 8]) = rb[c];
    }
#endif
    __syncthreads();
    #pragma unroll
    for (int kc = 0; kc < 2; ++kc) {
      const int pcs = ((kc * 4 + quad) ^ (ln & 7)) << 3;
      s16x8 af[4], bf[4];
      #pragma unroll
      for (int i = 0; i < 4; ++i)
        af[i] = *(const s16x8*)(&As[(wm * 64 + i * 16 + ln) * 64 + pcs]);
      #pragma unroll
      for (int j = 0; j < 4; ++j)
        bf[j] = *(const s16x8*)(&Bs[(wn * 64 + j * 16 + ln) * 64 + pcs]);
      #pragma unroll
      for (int i = 0; i < 4; ++i)
        #pragma unroll
        for (int j = 0; j < 4; ++j)
          acc[i][j] = __builtin_amdgcn_mfma_f32_16x16x32_bf16(af[i], bf[j], acc[i][j], 0, 0, 0);
    }
  }

  if constexpr (DO_SUMSQ) {
    if (bn >= 8 && bn < 12) {
      float ss = 0.0f;
      #pragma unroll
      for (int i = 0; i < 4; ++i)
        #pragma unroll
        for (int j = 0; j < 4; ++j)
          #pragma unroll
          for (int r = 0; r < 4; ++r)
            ss += acc[i][j][r] * acc[i][j][r];
      #pragma unroll
      for (int off = 1; off < 64; off <<= 1) ss += __shfl_xor(ss, off);
      if (lane == 0)
        atomicAdd(&sums[(m0 >> 10) * 8 + (bn - 8) * 2 + wn], ss);
    }
  }

  // Epilogue. C/D layout: row = quad*4+reg, col = lane&15.
  #pragma unroll
  for (int j = 0; j < 4; ++j) {
    const int gn = n0 + wn * 64 + j * 16 + ln;
    float bv = 0.0f;
    if constexpr (!OUT_BF16) bv = bias[gn];
    #pragma unroll
    for (int i = 0; i < 4; ++i) {
      const int gm0 = m0 + wm * 64 + i * 16 + quad * 4;
      #pragma unroll
      for (int r = 0; r < 4; ++r) {
        float v = acc[i][j][r];
        if constexpr (OUT_BF16) Cb[(gm0 + r) * N + gn] = f2bf(v);
        else                    Cf[(gm0 + r) * N + gn] = v + bv;
      }
    }
  }
}

// ---------------------------------------------------------------------------
// 3. Attention.  R11: block = 4 waves x 16 q = 64 queries of one (b,h);
//    grid = 2048 blocks -> 8 blocks/CU resident (LDS 17.4KB, VGPR<=64).
//    S^T form: sacc = mfma(K_frag, Q_frag) -> C-layout [key][q]; keys staged
//    permuted (Ks row m <- global key pi(m)) so exp2(sacc) packs DIRECTLY
//    into the PV B-fragment (P never touches LDS).  2 barriers/tile; the gll
//    drain at barrier (b) is covered by the 7 other resident blocks (TLP).
// ---------------------------------------------------------------------------
__global__ __launch_bounds__(256, 8)
void attn_kernel(const unsigned short* __restrict__ qkv,
                 const float* __restrict__ sums,
                 unsigned short* __restrict__ att) {
  __shared__ __align__(16) unsigned short Ks[4096];      // 64 keys x 64 d, swizzled+permuted
  __shared__ __align__(16) unsigned short Vt[64][72];    // Vt[d][key], natural order
  __shared__ int kvs;

  const int bid = blockIdx.x;
  const int h = bid & 15, qt = (bid >> 4) & 15, b = bid >> 8;
  const int t = threadIdx.x, w = t >> 6, lane = t & 63, quad = lane >> 4, ln = lane & 15;

  if (t == 0) {   // inline allocation (mirrors jax: round / first-argmax / searchsorted)
    float kn[8];
    for (int kv = 0; kv < 8; ++kv) {
      float s = 0.0f;
      for (int bb = 0; bb < 8; ++bb) s += sqrtf(sums[bb * 8 + kv]);
      kn[kv] = s;
    }
    float mn = kn[0], mx = kn[0];
    for (int i = 1; i < 8; ++i) { mn = fminf(mn, kn[i]); mx = fmaxf(mx, kn[i]); }
    float tot = 0.0f;
    for (int i = 0; i < 8; ++i) { kn[i] = (kn[i] - mn) / (mx - mn); tot += kn[i]; }
    int a[8], sum = 0;
    for (int i = 0; i < 8; ++i) { a[i] = (int)rintf(kn[i] * 16.0f / tot); sum += a[i]; }
    while (sum > 16) {
      int im = 0;
      for (int i = 1; i < 8; ++i) if (a[i] > a[im]) im = i;
      a[im]--; sum--;
    }
    while (sum < 16) {
      int im = 0;
      for (int i = 1; i < 8; ++i) if (a[i] < a[im]) im = i;
      a[im]++; sum++;
    }
    int cum = 0, idx = 0, c[8];
    for (int i = 0; i < 8; ++i) { cum += a[i]; c[i] = cum; }
    while (c[idx] <= h) idx++;
    kvs = idx;
  }
  __syncthreads();
  const int kvi = kvs;

  // Q fragments (B-operand of S^T): Q[q=ln][d=quad*8+j]
  s16x8 qf[2];
  {
    const unsigned short* qp = qkv + (b * 1024 + qt * 64 + w * 16 + ln) * 2048
                               + h * 64 + quad * 8;
    qf[0] = *(const s16x8*)(qp);
    qf[1] = *(const s16x8*)(qp + 32);
  }

  // K staging (gll, XOR chunk swizzle + key permutation pi):
  // Ks row m holds global key kt*64 + pi(m),  pi(m) = m5 | q1 q0 | ks0 | r1 r0.
  const int lc8 = ((lane & 7) ^ (lane >> 3)) << 3;
  const int mA = w * 16 + (lane >> 3);          // LDS rows staged by call A
  const int mB = mA + 8;                        // call B
  const int gA = (mA & 0x20) | ((mA & 0x0C) << 1) | ((mA & 0x10) >> 2) | (mA & 3);
  const int gB = (mB & 0x20) | ((mB & 0x0C) << 1) | ((mB & 0x10) >> 2) | (mB & 3);
  const unsigned short* kglA = qkv + (b * 1024 + gA) * 2048 + 1024 + kvi * 64 + lc8;
  const unsigned short* kglB = qkv + (b * 1024 + gB) * 2048 + 1024 + kvi * 64 + lc8;

  // V staging (natural key order): thread covers keys (2kp,2kp+1) x d [vd0,+8)
  const int kp = t & 31, vd0 = (t >> 5) << 3;
  const unsigned short* vbase = qkv + (b * 1024 + 2 * kp) * 2048 + 1536 + kvi * 64 + vd0;

  s16x8 ones;
  #pragma unroll
  for (int j = 0; j < 8; ++j) ones[j] = (short)0x3F80;   // bf16 1.0

  f32x4 Oa[4] = {};    // O^T frags: lane holds O^T[d=ds*16+quad*4+r][q=ln]
  f32x4 lacc = {};

  // V regs for tile 0 (issued pre-loop; first use is the tile-0 Vt write)
  s16x8 va0 = *(const s16x8*)(vbase);
  s16x8 va1 = *(const s16x8*)(vbase + 2048);

  for (int kt = 0; kt < 16; ++kt) {
    __syncthreads();   // (a) prior tile's compute done: Ks/Vt reusable.
                       //     also drains the V prefetch issued last compute.
#ifdef HAVE_GLL
    gll16(kglA + kt * 131072, Ks + w * 1024);
    gll16(kglB + kt * 131072, Ks + w * 1024 + 512);
#else
    i32x4 t0 = *(const i32x4*)(kglA + kt * 131072);
    i32x4 t1 = *(const i32x4*)(kglB + kt * 131072);
    *(i32x4*)(Ks + w * 1024 + lane * 8) = t0;
    *(i32x4*)(Ks + w * 1024 + 512 + lane * 8) = t1;
#endif
    #pragma unroll
    for (int i = 0; i < 8; ++i) {
      unsigned int pk = (unsigned int)(unsigned short)va0[i] |
                        ((unsigned int)(unsigned short)va1[i] << 16);
      *(unsigned int*)(&Vt[vd0 + i][2 * kp]) = pk;
    }
    __syncthreads();   // (b) staging visible (drains gll; TLP covers)

    // prefetch next tile's V regs at compute start: full tile of cover
    if (kt < 15) {
      const unsigned short* vq = vbase + (kt + 1) * 131072;
      va0 = *(const s16x8*)(vq);
      va1 = *(const s16x8*)(vq + 2048);
    }

    // K fragments (A-operand of S^T)
    s16x8 kfr[2][4];
    #pragma unroll
    for (int ks = 0; ks < 4; ++ks) {
      const int r0 = (ks * 16 + ln) * 64;
      kfr[0][ks] = *(const s16x8*)(Ks + r0 + (((quad    ) ^ (ln & 7)) << 3));
      kfr[1][ks] = *(const s16x8*)(Ks + r0 + (((quad + 4) ^ (ln & 7)) << 3));
    }

    // S^T:  sacc[ks][r] = S^T[slot 32*(ks>>1)+8*quad+4*(ks&1)+r][q=ln] (via pi)
    f32x4 sacc[4] = {};
    __builtin_amdgcn_s_setprio(1);
    #pragma unroll
    for (int ks = 0; ks < 4; ++ks) {
      sacc[ks] = __builtin_amdgcn_mfma_f32_16x16x32_bf16(kfr[0][ks], qf[0], sacc[ks], 0, 0, 0);
      sacc[ks] = __builtin_amdgcn_mfma_f32_16x16x32_bf16(kfr[1][ks], qf[1], sacc[ks], 0, 0, 0);
    }
    __builtin_amdgcn_s_setprio(0);

    // exp2 + pack P directly into PV B-fragments (no LDS):
    // pfs[kc] element j = P[slot kc*32+quad*8+j][q=ln]
    s16x8 pfs[2];
    #pragma unroll
    for (int kc = 0; kc < 2; ++kc) {
      i32x4 pd;
      pd[0] = (int)pk_bf16(fast_exp2(sacc[2*kc][0]),   fast_exp2(sacc[2*kc][1]));
      pd[1] = (int)pk_bf16(fast_exp2(sacc[2*kc][2]),   fast_exp2(sacc[2*kc][3]));
      pd[2] = (int)pk_bf16(fast_exp2(sacc[2*kc+1][0]), fast_exp2(sacc[2*kc+1][1]));
      pd[3] = (int)pk_bf16(fast_exp2(sacc[2*kc+1][2]), fast_exp2(sacc[2*kc+1][3]));
      pfs[kc] = __builtin_bit_cast(s16x8, pd);
    }

    // PV + l:  O^T[d][q] += V^T[d][slot] * P[slot][q];  A = V^T frag from Vt.
    __builtin_amdgcn_s_setprio(1);
    #pragma unroll
    for (int kc = 0; kc < 2; ++kc) {
      #pragma unroll
      for (int ds = 0; ds < 4; ++ds) {
        s16x8 vf = *(const s16x8*)(&Vt[ds * 16 + ln][kc * 32 + quad * 8]);
        Oa[ds] = __builtin_amdgcn_mfma_f32_16x16x32_bf16(vf, pfs[kc], Oa[ds], 0, 0, 0);
      }
      lacc = __builtin_amdgcn_mfma_f32_16x16x32_bf16(ones, pfs[kc], lacc, 0, 0, 0);
    }
    __builtin_amdgcn_s_setprio(0);
  }

  // finalize: O^T / l.  lacc rows all equal l[q=ln] -> ONE rcp per lane.
  // Store: lane holds 4 consecutive d per ds -> one 8B store each.
  {
    const float inv = 1.0f / lacc[0];
    unsigned short* orow = att + (b * 1024 + qt * 64 + w * 16 + ln) * 1024
                           + h * 64 + quad * 4;
    #pragma unroll
    for (int ds = 0; ds < 4; ++ds) {
      i32x2 pk;
      pk[0] = (int)pk_bf16(Oa[ds][0] * inv, Oa[ds][1] * inv);
      pk[1] = (int)pk_bf16(Oa[ds][2] * inv, Oa[ds][3] * inv);
      *(i32x2*)(orow + ds * 16) = pk;
    }
  }
}

// ---------------------------------------------------------------------------
// Workspace layout (bytes):
//   xb    @ 0          16,777,216   (bf16 8192x1024)  -- reused as att
//   wqkv  @ 16,777,216  4,194,304   (bf16 2048x1024: Wq*0.125*log2e | Wk | Wv)
//   wpb   @ 20,971,520  2,097,152   (bf16 1024x1024)
//   qkv   @ 23,068,672 33,554,432   (bf16 8192x2048)
//   sums  @ 56,623,104        256   (fp32 64: ||K||^2 per (b,kv))
// ---------------------------------------------------------------------------
extern "C" void kernel_launch(void* const* d_in, const int* in_sizes, int n_in,
                              void* d_out, int out_size, void* d_ws, size_t ws_size,
                              hipStream_t stream) {
  const float* x  = (const float*)d_in[0];
  const float* Wq = (const float*)d_in[1];
  const float* Wk = (const float*)d_in[2];
  const float* Wv = (const float*)d_in[3];
  const float* Wp = (const float*)d_in[4];
  const float* bp = (const float*)d_in[5];

  char* ws = (char*)d_ws;
  unsigned short* xb   = (unsigned short*)(ws);
  unsigned short* wqkv = (unsigned short*)(ws + 16777216);
  unsigned short* wpb  = (unsigned short*)(ws + 20971520);
  unsigned short* qkv  = (unsigned short*)(ws + 23068672);
  float*          sums = (float*)(ws + 56623104);
  unsigned short* att  = xb;   // xb dead after gemm1

  convert_kernel<<<11264, 256, 0, stream>>>(x, Wq, Wk, Wv, Wp, xb, wqkv, wpb, sums);
  gemm_bt<2048, true, true><<<1024, 256, 0, stream>>>(xb, wqkv, qkv, nullptr, nullptr, sums);
  attn_kernel<<<2048, 256, 0, stream>>>(qkv, sums, att);
  gemm_bt<1024, false, false><<<512, 256, 0, stream>>>(att, wpb, nullptr, (float*)d_out, bp, nullptr);
}

// Round 4
// 221.553 us; speedup vs baseline: 1.6222x; 1.6222x over previous
//
#include <hip/hip_runtime.h>
#include <stdint.h>

// ---------------------------------------------------------------------------
// KDGQA: x -> (Q,K,V) proj -> dynamic KV allocation from ||K||_F -> grouped
// attention -> output proj + bias.  B=8, P=1024, DIM=1024, H=16, KV=8, HD=64.
// R12: revert R11 (QBLK=64 exploded HBM: FETCH 26.7->242MB, attn 210us --
// cache could not filter the 16x K/V re-read; occupancy must not cost
// traffic).  Back to R10 structure (QBLK=128, 1024 blocks, dbuf, 1 barrier
// per tile).  NEW: gemm1 writes the V quarter of its output TRANSPOSED
// (vT[512][8192]) so attn stages V via global_load_lds exactly like K --
// removes per-tile 2 global loads + 16 VALU pack ops + 8 ds_writes per
// thread and the mid-loop vmcnt chain.  qkv shrinks to stride 1536 (Q|K),
// vT takes the freed space: total workspace unchanged (56.6 MB).
// V^T read-side bank conflicts handled by the same XOR chunk swizzle as K,
// applied via pre-swizzled global source (LDS dest stays gll-linear).
// ---------------------------------------------------------------------------

typedef float f32x4 __attribute__((ext_vector_type(4)));
typedef int   i32x2 __attribute__((ext_vector_type(2)));
typedef short s16x8 __attribute__((ext_vector_type(8)));
typedef short s16x4 __attribute__((ext_vector_type(4)));
typedef int   i32x4 __attribute__((ext_vector_type(4)));

__device__ __forceinline__ unsigned short f2bf(float f) {
  unsigned int u = __builtin_bit_cast(unsigned int, f);
  u = (u + 0x7FFFu + ((u >> 16) & 1u)) >> 16;   // round-to-nearest-even
  return (unsigned short)u;
}

// packed fp32x2 -> bf16x2 (low = a, high = b)
__device__ __forceinline__ unsigned int pk_bf16(float a, float b) {
#if __has_builtin(__builtin_amdgcn_cvt_pk_bf16_f32)
  auto v = __builtin_amdgcn_cvt_pk_bf16_f32(a, b);
  return __builtin_bit_cast(unsigned int, v);
#else
  unsigned int ua = __builtin_bit_cast(unsigned int, a);
  unsigned int ub = __builtin_bit_cast(unsigned int, b);
  ua += 0x7FFFu + ((ua >> 16) & 1u);
  ub += 0x7FFFu + ((ub >> 16) & 1u);
#if __has_builtin(__builtin_amdgcn_perm)
  return __builtin_amdgcn_perm(ub, ua, 0x07060302);
#else
  return (ua >> 16) | (ub & 0xFFFF0000u);
#endif
#endif
}

__device__ __forceinline__ float fast_exp2(float x) {
#if __has_builtin(__builtin_amdgcn_exp2f)
  return __builtin_amdgcn_exp2f(x);
#else
  return exp2f(x);
#endif
}

#if __has_builtin(__builtin_amdgcn_global_load_lds)
#define HAVE_GLL 1
typedef const __attribute__((address_space(1))) void* gas_ptr;
typedef __attribute__((address_space(3))) void* las_ptr;
__device__ __forceinline__ void gll16(const void* g, void* l) {
  __builtin_amdgcn_global_load_lds((gas_ptr)g, (las_ptr)l, 16, 0, 0);
}
#endif

// ---------------------------------------------------------------------------
// 1. fp32 -> bf16 conversion. Wq gets 0.125 (HD^-0.5) * log2(e) folded in so
//    attention softmax is a raw exp2.  Block 0 also zeroes the sumsq cells.
// ---------------------------------------------------------------------------
__global__ void convert_kernel(const float* __restrict__ x, const float* __restrict__ Wq,
                               const float* __restrict__ Wk, const float* __restrict__ Wv,
                               const float* __restrict__ Wp,
                               unsigned short* __restrict__ xb,
                               unsigned short* __restrict__ wqkv,
                               unsigned short* __restrict__ wpb,
                               float* __restrict__ sums) {
  if (blockIdx.x == 0 && threadIdx.x < 64) sums[threadIdx.x] = 0.0f;
  const long i = ((long)blockIdx.x * 256 + threadIdx.x) * 4;
  const float* src; unsigned short* dst; long off; float scale = 1.0f;
  if (i < 8388608L)       { src = x;  dst = xb;             off = i;             }
  else if (i < 9437184L)  { src = Wq; dst = wqkv;           off = i - 8388608L;  scale = 0.18033688011112042f; }
  else if (i < 9961472L)  { src = Wk; dst = wqkv + 1048576; off = i - 9437184L;  }
  else if (i < 10485760L) { src = Wv; dst = wqkv + 1572864; off = i - 9961472L;  }
  else                    { src = Wp; dst = wpb;            off = i - 10485760L; }
  f32x4 v = *(const f32x4*)(src + off);
  s16x4 o;
  o[0] = (short)f2bf(v[0] * scale);
  o[1] = (short)f2bf(v[1] * scale);
  o[2] = (short)f2bf(v[2] * scale);
  o[3] = (short)f2bf(v[3] * scale);
  *(s16x4*)(dst + off) = o;
}

// ---------------------------------------------------------------------------
// 2. GEMM  C[M][N] = A[M][1024] * B[N][1024]^T, 128x128 tile, BK=64, m97-style
//    global_load_lds staging with XOR chunk swizzle.  DO_SUMSQ: K-range blocks
//    reduce sum(acc^2) per (b, kv head) into sums[] via one atomic per wave.
//    R12: OSTR decouples output stride from N; columns >=1536 of gemm1 (the V
//    projection) are written TRANSPOSED to vt[512][8192] (V^T) instead of Cb.
// ---------------------------------------------------------------------------
template<int N, int OSTR, bool OUT_BF16, bool DO_SUMSQ>
__global__ __launch_bounds__(256)
void gemm_bt(const unsigned short* __restrict__ A,
             const unsigned short* __restrict__ Bw,
             unsigned short* __restrict__ Cb,
             float* __restrict__ Cf,
             const float* __restrict__ bias,
             float* __restrict__ sums,
             unsigned short* __restrict__ vt) {
  __shared__ __align__(16) unsigned short As[8192];   // 128 rows x 64 shorts
  __shared__ __align__(16) unsigned short Bs[8192];
  constexpr int NB = N / 128;
  const int bm = blockIdx.x / NB, bn = blockIdx.x % NB;
  const int m0 = bm * 128, n0 = bn * 128;
  const int t = threadIdx.x;
  const int w = t >> 6, lane = t & 63, quad = lane >> 4, ln = lane & 15;
  const int wm = w & 1, wn = w >> 1;

  const int lrow = lane >> 3;                       // 0..7
  const int lc8  = ((lane & 7) ^ lrow) << 3;        // logical chunk offset (shorts)
  const unsigned short* agl = A  + (m0 + w * 32 + lrow) * 1024 + lc8;
  const unsigned short* bgl = Bw + (n0 + w * 32 + lrow) * 1024 + lc8;

  f32x4 acc[4][4] = {};

  for (int k0 = 0; k0 < 1024; k0 += 64) {
    __syncthreads();
#ifdef HAVE_GLL
    #pragma unroll
    for (int c = 0; c < 4; ++c) {
      gll16(agl + k0 + c * 8192, &As[w * 2048 + c * 512]);
      gll16(bgl + k0 + c * 8192, &Bs[w * 2048 + c * 512]);
    }
#else
    i32x4 ra[4], rb[4];
    #pragma unroll
    for (int c = 0; c < 4; ++c) {
      ra[c] = *(const i32x4*)(agl + k0 + c * 8192);
      rb[c] = *(const i32x4*)(bgl + k0 + c * 8192);
    }
    #pragma unroll
    for (int c = 0; c < 4; ++c) {
      *(i32x4*)(&As[w * 2048 + c * 512 + lane * 8]) = ra[c];
      *(i32x4*)(&Bs[w * 2048 + c * 512 + lane * 8]) = rb[c];
    }
#endif
    __syncthreads();
    #pragma unroll
    for (int kc = 0; kc < 2; ++kc) {
      const int pcs = ((kc * 4 + quad) ^ (ln & 7)) << 3;
      s16x8 af[4], bf[4];
      #pragma unroll
      for (int i = 0; i < 4; ++i)
        af[i] = *(const s16x8*)(&As[(wm * 64 + i * 16 + ln) * 64 + pcs]);
      #pragma unroll
      for (int j = 0; j < 4; ++j)
        bf[j] = *(const s16x8*)(&Bs[(wn * 64 + j * 16 + ln) * 64 + pcs]);
      #pragma unroll
      for (int i = 0; i < 4; ++i)
        #pragma unroll
        for (int j = 0; j < 4; ++j)
          acc[i][j] = __builtin_amdgcn_mfma_f32_16x16x32_bf16(af[i], bf[j], acc[i][j], 0, 0, 0);
    }
  }

  if constexpr (DO_SUMSQ) {
    if (bn >= 8 && bn < 12) {
      float ss = 0.0f;
      #pragma unroll
      for (int i = 0; i < 4; ++i)
        #pragma unroll
        for (int j = 0; j < 4; ++j)
          #pragma unroll
          for (int r = 0; r < 4; ++r)
            ss += acc[i][j][r] * acc[i][j][r];
      #pragma unroll
      for (int off = 1; off < 64; off <<= 1) ss += __shfl_xor(ss, off);
      if (lane == 0)
        atomicAdd(&sums[(m0 >> 10) * 8 + (bn - 8) * 2 + wn], ss);
    }
  }

  // Epilogue. C/D layout: row = quad*4+reg, col = lane&15.
  // V columns (gn >= 1536, gemm1 only): write V^T to vt[gn-1536][gm] -- the
  // 4 acc regs are consecutive gm -> one 8B packed store.  Uniform per block
  // (n0 multiple of 128; 1536 = 12*128) -> no divergence.
  #pragma unroll
  for (int j = 0; j < 4; ++j) {
    const int gn = n0 + wn * 64 + j * 16 + ln;
    float bv = 0.0f;
    if constexpr (!OUT_BF16) bv = bias[gn];
    #pragma unroll
    for (int i = 0; i < 4; ++i) {
      const int gm0 = m0 + wm * 64 + i * 16 + quad * 4;
      if (OUT_BF16 && vt != nullptr && gn >= 1536) {
        unsigned short* vp = vt + (long)(gn - 1536) * 8192 + gm0;
        i32x2 pk;
        pk[0] = (int)pk_bf16(acc[i][j][0], acc[i][j][1]);
        pk[1] = (int)pk_bf16(acc[i][j][2], acc[i][j][3]);
        *(i32x2*)vp = pk;
      } else {
        #pragma unroll
        for (int r = 0; r < 4; ++r) {
          float v = acc[i][j][r];
          if constexpr (OUT_BF16) Cb[(long)(gm0 + r) * OSTR + gn] = f2bf(v);
          else                    Cf[(long)(gm0 + r) * OSTR + gn] = v + bv;
        }
      }
    }
  }
}

// ---------------------------------------------------------------------------
// 3. Attention. Block = 4 waves x 2 strips x 16 q = 128 queries of one (b,h).
//    S^T form: sacc = mfma(K_frag, Q_frag) -> C-layout [key][q]; keys staged
//    permuted (Ks row m <- global key pi(m)) so exp2(sacc) packs DIRECTLY
//    into the PV B-fragment (P never touches LDS).
//    R12: V^T precomputed by gemm1 -> V staged via gll like K (no VALU pack,
//    no reg round-trip).  Dbuf both, single barrier/tile; all staging is gll
//    so the barrier's vmcnt(0) drain has a full tile of compute cover.
// ---------------------------------------------------------------------------
__global__ __launch_bounds__(256, 4)
void attn_kernel(const unsigned short* __restrict__ qkv,
                 const unsigned short* __restrict__ vT,
                 const float* __restrict__ sums,
                 unsigned short* __restrict__ att) {
  __shared__ __align__(16) unsigned short Ks[2][4096];   // 64 keys x 64 d, swizzled+permuted
  __shared__ __align__(16) unsigned short Vt[2][4096];   // V^T: 64 d x 64 keys, chunk-swizzled
  __shared__ int kvs;

  const int bid = blockIdx.x;
  const int h = bid & 15, qt = (bid >> 4) & 7, b = bid >> 7;
  const int t = threadIdx.x, w = t >> 6, lane = t & 63, quad = lane >> 4, ln = lane & 15;

  if (t == 0) {   // inline allocation (mirrors jax: round / first-argmax / searchsorted)
    float kn[8];
    for (int kv = 0; kv < 8; ++kv) {
      float s = 0.0f;
      for (int bb = 0; bb < 8; ++bb) s += sqrtf(sums[bb * 8 + kv]);
      kn[kv] = s;
    }
    float mn = kn[0], mx = kn[0];
    for (int i = 1; i < 8; ++i) { mn = fminf(mn, kn[i]); mx = fmaxf(mx, kn[i]); }
    float tot = 0.0f;
    for (int i = 0; i < 8; ++i) { kn[i] = (kn[i] - mn) / (mx - mn); tot += kn[i]; }
    int a[8], sum = 0;
    for (int i = 0; i < 8; ++i) { a[i] = (int)rintf(kn[i] * 16.0f / tot); sum += a[i]; }
    while (sum > 16) {
      int im = 0;
      for (int i = 1; i < 8; ++i) if (a[i] > a[im]) im = i;
      a[im]--; sum--;
    }
    while (sum < 16) {
      int im = 0;
      for (int i = 1; i < 8; ++i) if (a[i] < a[im]) im = i;
      a[im]++; sum++;
    }
    int cum = 0, idx = 0, c[8];
    for (int i = 0; i < 8; ++i) { cum += a[i]; c[i] = cum; }
    while (c[idx] <= h) idx++;
    kvs = idx;
  }
  __syncthreads();
  const int kvi = kvs;

  // Q fragments for both strips (B-operand of S^T): Q[q=ln][d=quad*8+j]
  s16x8 qf[2][2];
  #pragma unroll
  for (int s = 0; s < 2; ++s) {
    const unsigned short* qp = qkv + (long)(b * 1024 + qt * 128 + s * 64 + w * 16 + ln) * 1536
                               + h * 64 + quad * 8;
    qf[s][0] = *(const s16x8*)(qp);
    qf[s][1] = *(const s16x8*)(qp + 32);
  }

  // K staging (gll, XOR chunk swizzle + key permutation pi):
  // Ks row m holds global key kt*64 + pi(m),  pi(m) = m5 | q1 q0 | ks0 | r1 r0.
  const int lc8 = ((lane & 7) ^ (lane >> 3)) << 3;
  const int mA = w * 16 + (lane >> 3);          // LDS rows staged by call A
  const int mB = mA + 8;                        // call B
  const int gA = (mA & 0x20) | ((mA & 0x0C) << 1) | ((mA & 0x10) >> 2) | (mA & 3);
  const int gB = (mB & 0x20) | ((mB & 0x0C) << 1) | ((mB & 0x10) >> 2) | (mB & 3);
  const unsigned short* kglA = qkv + (long)(b * 1024 + gA) * 1536 + 1024 + kvi * 64 + lc8;
  const unsigned short* kglB = qkv + (long)(b * 1024 + gB) * 1536 + 1024 + kvi * 64 + lc8;

  // V^T staging (gll from vT[512][8192], natural d order, chunk-swizzled
  // source so the LDS-linear dest carries the XOR pattern):
  // Vt row r (=d) holds key chunks c at swizzled position c ^ (r&7).
  const unsigned short* vglA = vT + (long)(kvi * 64 + mA) * 8192 + b * 1024 + lc8;
  const unsigned short* vglB = vglA + 8 * 8192;

  s16x8 ones;
  #pragma unroll
  for (int j = 0; j < 8; ++j) ones[j] = (short)0x3F80;   // bf16 1.0

  f32x4 Oa[2][4] = {};    // O^T frags: lane holds O^T[d=ds*16+quad*4+r][q=ln]
  f32x4 lacc[2] = {};

  // ---- prologue: stage tile 0 into buffer 0 ----
#ifdef HAVE_GLL
  gll16(kglA, &Ks[0][w * 1024]);
  gll16(kglB, &Ks[0][w * 1024 + 512]);
  gll16(vglA, &Vt[0][w * 1024]);
  gll16(vglB, &Vt[0][w * 1024 + 512]);
#else
  {
    i32x4 t0 = *(const i32x4*)(kglA);
    i32x4 t1 = *(const i32x4*)(kglB);
    i32x4 t2 = *(const i32x4*)(vglA);
    i32x4 t3 = *(const i32x4*)(vglB);
    *(i32x4*)(&Ks[0][w * 1024 + lane * 8]) = t0;
    *(i32x4*)(&Ks[0][w * 1024 + 512 + lane * 8]) = t1;
    *(i32x4*)(&Vt[0][w * 1024 + lane * 8]) = t2;
    *(i32x4*)(&Vt[0][w * 1024 + 512 + lane * 8]) = t3;
  }
#endif
  __syncthreads();

  for (int kt = 0; kt < 16; ++kt) {
    const int cur = kt & 1, nxt = cur ^ 1;

    // -- 1. next tile's staging (all gll; drains at end-of-iter barrier,
    //       a full tile of compute away) --
    if (kt < 15) {
      const long ko = (long)(kt + 1) * 98304;   // 64 rows * 1536
      const long vo = (kt + 1) * 64;            // 64 keys along vT rows
#ifdef HAVE_GLL
      gll16(kglA + ko, &Ks[nxt][w * 1024]);
      gll16(kglB + ko, &Ks[nxt][w * 1024 + 512]);
      gll16(vglA + vo, &Vt[nxt][w * 1024]);
      gll16(vglB + vo, &Vt[nxt][w * 1024 + 512]);
#else
      i32x4 t0 = *(const i32x4*)(kglA + ko);
      i32x4 t1 = *(const i32x4*)(kglB + ko);
      i32x4 t2 = *(const i32x4*)(vglA + vo);
      i32x4 t3 = *(const i32x4*)(vglB + vo);
      *(i32x4*)(&Ks[nxt][w * 1024 + lane * 8]) = t0;
      *(i32x4*)(&Ks[nxt][w * 1024 + 512 + lane * 8]) = t1;
      *(i32x4*)(&Vt[nxt][w * 1024 + lane * 8]) = t2;
      *(i32x4*)(&Vt[nxt][w * 1024 + 512 + lane * 8]) = t3;
#endif
    }

    // -- 2. K fragments for CURRENT tile (A-operand of S^T) --
    s16x8 kfr[2][4];
    #pragma unroll
    for (int ks = 0; ks < 4; ++ks) {
      const int r0 = (ks * 16 + ln) * 64;
      kfr[0][ks] = *(const s16x8*)(&Ks[cur][r0 + (((quad    ) ^ (ln & 7)) << 3)]);
      kfr[1][ks] = *(const s16x8*)(&Ks[cur][r0 + (((quad + 4) ^ (ln & 7)) << 3)]);
    }

    // -- 3. S^T per strip, then pack P directly into PV B-fragments (no LDS)
    // sacc[ks][r] = S^T[slot 32*(ks>>1)+8*quad+4*(ks&1)+r][q=ln]  (via pi)
    // pf[kc] element j = P[slot kc*32+quad*8+j][q=ln]
    s16x8 pfs[2][2];
    #pragma unroll
    for (int s = 0; s < 2; ++s) {
      f32x4 sacc[4] = {};
      __builtin_amdgcn_s_setprio(1);
      #pragma unroll
      for (int ks = 0; ks < 4; ++ks) {
        sacc[ks] = __builtin_amdgcn_mfma_f32_16x16x32_bf16(kfr[0][ks], qf[s][0], sacc[ks], 0, 0, 0);
        sacc[ks] = __builtin_amdgcn_mfma_f32_16x16x32_bf16(kfr[1][ks], qf[s][1], sacc[ks], 0, 0, 0);
      }
      __builtin_amdgcn_s_setprio(0);
      #pragma unroll
      for (int kc = 0; kc < 2; ++kc) {
        i32x4 pd;
        pd[0] = (int)pk_bf16(fast_exp2(sacc[2*kc][0]),   fast_exp2(sacc[2*kc][1]));
        pd[1] = (int)pk_bf16(fast_exp2(sacc[2*kc][2]),   fast_exp2(sacc[2*kc][3]));
        pd[2] = (int)pk_bf16(fast_exp2(sacc[2*kc+1][0]), fast_exp2(sacc[2*kc+1][1]));
        pd[3] = (int)pk_bf16(fast_exp2(sacc[2*kc+1][2]), fast_exp2(sacc[2*kc+1][3]));
        pfs[s][kc] = __builtin_bit_cast(s16x8, pd);
      }
    }

    // -- 4. PV + l:  O^T[d][q] += V^T[d][slot] * P[slot][q];  A from Vt[cur].
    //       vf read: row r = ds*16+ln, key chunk (kc*4+quad) at swizzled
    //       position (kc*4+quad) ^ (ln&7)  (matches the staged source swz).
    __builtin_amdgcn_s_setprio(1);
    #pragma unroll
    for (int kc = 0; kc < 2; ++kc) {
      #pragma unroll
      for (int ds = 0; ds < 4; ++ds) {
        s16x8 vf = *(const s16x8*)(&Vt[cur][(ds * 16 + ln) * 64 +
                                            (((kc * 4 + quad) ^ (ln & 7)) << 3)]);
        Oa[0][ds] = __builtin_amdgcn_mfma_f32_16x16x32_bf16(vf, pfs[0][kc], Oa[0][ds], 0, 0, 0);
        Oa[1][ds] = __builtin_amdgcn_mfma_f32_16x16x32_bf16(vf, pfs[1][kc], Oa[1][ds], 0, 0, 0);
      }
      lacc[0] = __builtin_amdgcn_mfma_f32_16x16x32_bf16(ones, pfs[0][kc], lacc[0], 0, 0, 0);
      lacc[1] = __builtin_amdgcn_mfma_f32_16x16x32_bf16(ones, pfs[1][kc], lacc[1], 0, 0, 0);
    }
    __builtin_amdgcn_s_setprio(0);

    __syncthreads();   // single barrier/tile: publishes [nxt], retires [cur]
  }

  // finalize: O^T / l.  lacc rows all equal l[q=ln] -> ONE rcp per lane/strip.
  // Store: lane holds 4 consecutive d per ds -> one 8B store each.
  #pragma unroll
  for (int s = 0; s < 2; ++s) {
    const float inv = 1.0f / lacc[s][0];
    unsigned short* orow = att + (long)(b * 1024 + qt * 128 + s * 64 + w * 16 + ln) * 1024
                           + h * 64 + quad * 4;
    #pragma unroll
    for (int ds = 0; ds < 4; ++ds) {
      i32x2 pk;
      pk[0] = (int)pk_bf16(Oa[s][ds][0] * inv, Oa[s][ds][1] * inv);
      pk[1] = (int)pk_bf16(Oa[s][ds][2] * inv, Oa[s][ds][3] * inv);
      *(i32x2*)(orow + ds * 16) = pk;
    }
  }
}

// ---------------------------------------------------------------------------
// Workspace layout (bytes):
//   xb    @ 0          16,777,216   (bf16 8192x1024)  -- reused as att
//   wqkv  @ 16,777,216  4,194,304   (bf16 2048x1024: Wq*0.125*log2e | Wk | Wv)
//   wpb   @ 20,971,520  2,097,152   (bf16 1024x1024)
//   qkv   @ 23,068,672 25,165,824   (bf16 8192x1536: Q | K)
//   vT    @ 48,234,496  8,388,608   (bf16 512x8192: V^T, d-major)
//   sums  @ 56,623,104        256   (fp32 64: ||K||^2 per (b,kv))
// ---------------------------------------------------------------------------
extern "C" void kernel_launch(void* const* d_in, const int* in_sizes, int n_in,
                              void* d_out, int out_size, void* d_ws, size_t ws_size,
                              hipStream_t stream) {
  const float* x  = (const float*)d_in[0];
  const float* Wq = (const float*)d_in[1];
  const float* Wk = (const float*)d_in[2];
  const float* Wv = (const float*)d_in[3];
  const float* Wp = (const float*)d_in[4];
  const float* bp = (const float*)d_in[5];

  char* ws = (char*)d_ws;
  unsigned short* xb   = (unsigned short*)(ws);
  unsigned short* wqkv = (unsigned short*)(ws + 16777216);
  unsigned short* wpb  = (unsigned short*)(ws + 20971520);
  unsigned short* qkv  = (unsigned short*)(ws + 23068672);
  unsigned short* vT   = (unsigned short*)(ws + 48234496);
  float*          sums = (float*)(ws + 56623104);
  unsigned short* att  = xb;   // xb dead after gemm1

  convert_kernel<<<11264, 256, 0, stream>>>(x, Wq, Wk, Wv, Wp, xb, wqkv, wpb, sums);
  gemm_bt<2048, 1536, true, true><<<1024, 256, 0, stream>>>(xb, wqkv, qkv, nullptr, nullptr, sums, vT);
  attn_kernel<<<1024, 256, 0, stream>>>(qkv, vT, sums, att);
  gemm_bt<1024, 1024, false, false><<<512, 256, 0, stream>>>(att, wpb, nullptr, (float*)d_out, bp, nullptr, nullptr);
}

// Round 5
// 211.113 us; speedup vs baseline: 1.7024x; 1.0495x over previous
//
#include <hip/hip_runtime.h>
#include <stdint.h>

// ---------------------------------------------------------------------------
// KDGQA: x -> (Q,K,V) proj -> dynamic KV allocation from ||K||_F -> grouped
// attention -> output proj + bias.  B=8, P=1024, DIM=1024, H=16, KV=8, HD=64.
// R13: fix R12's vT production.  R12 wrote V^T in gemm1's epilogue as 8B
// stores at 16KB stride (64 cache lines per store instr) -> ~14us gemm1
// regression.  Now V-region blocks (n0>=1536) SWAP the staging pointers:
// A-operand stages Wv rows (n-side), B-operand stages x rows (m-side).  The
// MFMA loop is textually identical; acc holds C^T directly and the epilogue
// writes vT with lanes -> consecutive columns (32B contiguous per row).
// attn: unchanged R12 structure (56.5us, 0 bank conflicts) + hoisted-zero
// C-in for the first S^T MFMA (kills 32 v_mov zero-inits per tile).
// ---------------------------------------------------------------------------

typedef float f32x4 __attribute__((ext_vector_type(4)));
typedef int   i32x2 __attribute__((ext_vector_type(2)));
typedef short s16x8 __attribute__((ext_vector_type(8)));
typedef short s16x4 __attribute__((ext_vector_type(4)));
typedef int   i32x4 __attribute__((ext_vector_type(4)));

__device__ __forceinline__ unsigned short f2bf(float f) {
  unsigned int u = __builtin_bit_cast(unsigned int, f);
  u = (u + 0x7FFFu + ((u >> 16) & 1u)) >> 16;   // round-to-nearest-even
  return (unsigned short)u;
}

// packed fp32x2 -> bf16x2 (low = a, high = b)
__device__ __forceinline__ unsigned int pk_bf16(float a, float b) {
#if __has_builtin(__builtin_amdgcn_cvt_pk_bf16_f32)
  auto v = __builtin_amdgcn_cvt_pk_bf16_f32(a, b);
  return __builtin_bit_cast(unsigned int, v);
#else
  unsigned int ua = __builtin_bit_cast(unsigned int, a);
  unsigned int ub = __builtin_bit_cast(unsigned int, b);
  ua += 0x7FFFu + ((ua >> 16) & 1u);
  ub += 0x7FFFu + ((ub >> 16) & 1u);
#if __has_builtin(__builtin_amdgcn_perm)
  return __builtin_amdgcn_perm(ub, ua, 0x07060302);
#else
  return (ua >> 16) | (ub & 0xFFFF0000u);
#endif
#endif
}

__device__ __forceinline__ float fast_exp2(float x) {
#if __has_builtin(__builtin_amdgcn_exp2f)
  return __builtin_amdgcn_exp2f(x);
#else
  return exp2f(x);
#endif
}

#if __has_builtin(__builtin_amdgcn_global_load_lds)
#define HAVE_GLL 1
typedef const __attribute__((address_space(1))) void* gas_ptr;
typedef __attribute__((address_space(3))) void* las_ptr;
__device__ __forceinline__ void gll16(const void* g, void* l) {
  __builtin_amdgcn_global_load_lds((gas_ptr)g, (las_ptr)l, 16, 0, 0);
}
#endif

// ---------------------------------------------------------------------------
// 1. fp32 -> bf16 conversion. Wq gets 0.125 (HD^-0.5) * log2(e) folded in so
//    attention softmax is a raw exp2.  Block 0 also zeroes the sumsq cells.
// ---------------------------------------------------------------------------
__global__ void convert_kernel(const float* __restrict__ x, const float* __restrict__ Wq,
                               const float* __restrict__ Wk, const float* __restrict__ Wv,
                               const float* __restrict__ Wp,
                               unsigned short* __restrict__ xb,
                               unsigned short* __restrict__ wqkv,
                               unsigned short* __restrict__ wpb,
                               float* __restrict__ sums) {
  if (blockIdx.x == 0 && threadIdx.x < 64) sums[threadIdx.x] = 0.0f;
  const long i = ((long)blockIdx.x * 256 + threadIdx.x) * 4;
  const float* src; unsigned short* dst; long off; float scale = 1.0f;
  if (i < 8388608L)       { src = x;  dst = xb;             off = i;             }
  else if (i < 9437184L)  { src = Wq; dst = wqkv;           off = i - 8388608L;  scale = 0.18033688011112042f; }
  else if (i < 9961472L)  { src = Wk; dst = wqkv + 1048576; off = i - 9437184L;  }
  else if (i < 10485760L) { src = Wv; dst = wqkv + 1572864; off = i - 9961472L;  }
  else                    { src = Wp; dst = wpb;            off = i - 10485760L; }
  f32x4 v = *(const f32x4*)(src + off);
  s16x4 o;
  o[0] = (short)f2bf(v[0] * scale);
  o[1] = (short)f2bf(v[1] * scale);
  o[2] = (short)f2bf(v[2] * scale);
  o[3] = (short)f2bf(v[3] * scale);
  *(s16x4*)(dst + off) = o;
}

// ---------------------------------------------------------------------------
// 2. GEMM  C[M][N] = A[M][1024] * B[N][1024]^T, 128x128 tile, BK=64, m97-style
//    global_load_lds staging with XOR chunk swizzle.  DO_SUMSQ: K-range blocks
//    reduce sum(acc^2) per (b, kv head) into sums[] via one atomic per wave.
//    R13: V-region blocks (gemm1, n0>=1536) swap staging pointers so acc
//    holds C^T; epilogue writes vT[512][8192] coalesced (no hot-loop change).
// ---------------------------------------------------------------------------
template<int N, int OSTR, bool OUT_BF16, bool DO_SUMSQ>
__global__ __launch_bounds__(256)
void gemm_bt(const unsigned short* __restrict__ A,
             const unsigned short* __restrict__ Bw,
             unsigned short* __restrict__ Cb,
             float* __restrict__ Cf,
             const float* __restrict__ bias,
             float* __restrict__ sums,
             unsigned short* __restrict__ vt) {
  __shared__ __align__(16) unsigned short As[8192];   // 128 rows x 64 shorts
  __shared__ __align__(16) unsigned short Bs[8192];
  constexpr int NB = N / 128;
  const int bm = blockIdx.x / NB, bn = blockIdx.x % NB;
  const int m0 = bm * 128, n0 = bn * 128;
  const int t = threadIdx.x;
  const int w = t >> 6, lane = t & 63, quad = lane >> 4, ln = lane & 15;
  const int wm = w & 1, wn = w >> 1;

  // V-region blocks: swap operands so the MFMA produces C^T (n-side on the
  // A-operand).  Block-uniform; MFMA loop below is identical either way.
  const bool vblk = OUT_BF16 && (vt != nullptr) && (n0 >= 1536);
  const unsigned short* Abase = vblk ? Bw : A;
  const unsigned short* Bbase = vblk ? A  : Bw;
  const int ar0 = vblk ? n0 : m0;
  const int br0 = vblk ? m0 : n0;

  const int lrow = lane >> 3;                       // 0..7
  const int lc8  = ((lane & 7) ^ lrow) << 3;        // logical chunk offset (shorts)
  const unsigned short* agl = Abase + (ar0 + w * 32 + lrow) * 1024 + lc8;
  const unsigned short* bgl = Bbase + (br0 + w * 32 + lrow) * 1024 + lc8;

  f32x4 acc[4][4] = {};

  for (int k0 = 0; k0 < 1024; k0 += 64) {
    __syncthreads();
#ifdef HAVE_GLL
    #pragma unroll
    for (int c = 0; c < 4; ++c) {
      gll16(agl + k0 + c * 8192, &As[w * 2048 + c * 512]);
      gll16(bgl + k0 + c * 8192, &Bs[w * 2048 + c * 512]);
    }
#else
    i32x4 ra[4], rb[4];
    #pragma unroll
    for (int c = 0; c < 4; ++c) {
      ra[c] = *(const i32x4*)(agl + k0 + c * 8192);
      rb[c] = *(const i32x4*)(bgl + k0 + c * 8192);
    }
    #pragma unroll
    for (int c = 0; c < 4; ++c) {
      *(i32x4*)(&As[w * 2048 + c * 512 + lane * 8]) = ra[c];
      *(i32x4*)(&Bs[w * 2048 + c * 512 + lane * 8]) = rb[c];
    }
#endif
    __syncthreads();
    #pragma unroll
    for (int kc = 0; kc < 2; ++kc) {
      const int pcs = ((kc * 4 + quad) ^ (ln & 7)) << 3;
      s16x8 af[4], bf[4];
      #pragma unroll
      for (int i = 0; i < 4; ++i)
        af[i] = *(const s16x8*)(&As[(wm * 64 + i * 16 + ln) * 64 + pcs]);
      #pragma unroll
      for (int j = 0; j < 4; ++j)
        bf[j] = *(const s16x8*)(&Bs[(wn * 64 + j * 16 + ln) * 64 + pcs]);
      #pragma unroll
      for (int i = 0; i < 4; ++i)
        #pragma unroll
        for (int j = 0; j < 4; ++j)
          acc[i][j] = __builtin_amdgcn_mfma_f32_16x16x32_bf16(af[i], bf[j], acc[i][j], 0, 0, 0);
    }
  }

  if constexpr (DO_SUMSQ) {
    if (bn >= 8 && bn < 12) {
      float ss = 0.0f;
      #pragma unroll
      for (int i = 0; i < 4; ++i)
        #pragma unroll
        for (int j = 0; j < 4; ++j)
          #pragma unroll
          for (int r = 0; r < 4; ++r)
            ss += acc[i][j][r] * acc[i][j][r];
      #pragma unroll
      for (int off = 1; off < 64; off <<= 1) ss += __shfl_xor(ss, off);
      if (lane == 0)
        atomicAdd(&sums[(m0 >> 10) * 8 + (bn - 8) * 2 + wn], ss);
    }
  }

  if (vblk) {
    // acc = C^T tile: row (quad*4+r) = n-offset in [wm*64+i*16, +16),
    // col (ln) = m-offset in [wn*64+j*16, +16).  vT[512][8192]:
    // 16 lanes -> 16 consecutive columns (32B contiguous per row).
    #pragma unroll
    for (int j = 0; j < 4; ++j) {
      const int vcol = m0 + wn * 64 + j * 16 + ln;
      #pragma unroll
      for (int i = 0; i < 4; ++i) {
        const int vr0 = (n0 - 1536) + wm * 64 + i * 16 + quad * 4;
        #pragma unroll
        for (int r = 0; r < 4; ++r)
          vt[(long)(vr0 + r) * 8192 + vcol] = f2bf(acc[i][j][r]);
      }
    }
    return;
  }

  // Epilogue. C/D layout: row = quad*4+reg, col = lane&15.
  #pragma unroll
  for (int j = 0; j < 4; ++j) {
    const int gn = n0 + wn * 64 + j * 16 + ln;
    float bv = 0.0f;
    if constexpr (!OUT_BF16) bv = bias[gn];
    #pragma unroll
    for (int i = 0; i < 4; ++i) {
      const int gm0 = m0 + wm * 64 + i * 16 + quad * 4;
      #pragma unroll
      for (int r = 0; r < 4; ++r) {
        float v = acc[i][j][r];
        if constexpr (OUT_BF16) Cb[(long)(gm0 + r) * OSTR + gn] = f2bf(v);
        else                    Cf[(long)(gm0 + r) * OSTR + gn] = v + bv;
      }
    }
  }
}

// ---------------------------------------------------------------------------
// 3. Attention. Block = 4 waves x 2 strips x 16 q = 128 queries of one (b,h).
//    S^T form: sacc = mfma(K_frag, Q_frag) -> C-layout [key][q]; keys staged
//    permuted (Ks row m <- global key pi(m)) so exp2(sacc) packs DIRECTLY
//    into the PV B-fragment (P never touches LDS).
//    V^T precomputed by gemm1 -> V staged via gll like K.  Dbuf both, single
//    barrier/tile; all staging is gll so the barrier's vmcnt(0) drain has a
//    full tile of compute cover.  R13: hoisted-zero C-in for S^T MFMAs.
// ---------------------------------------------------------------------------
__global__ __launch_bounds__(256, 4)
void attn_kernel(const unsigned short* __restrict__ qkv,
                 const unsigned short* __restrict__ vT,
                 const float* __restrict__ sums,
                 unsigned short* __restrict__ att) {
  __shared__ __align__(16) unsigned short Ks[2][4096];   // 64 keys x 64 d, swizzled+permuted
  __shared__ __align__(16) unsigned short Vt[2][4096];   // V^T: 64 d x 64 keys, chunk-swizzled
  __shared__ int kvs;

  const int bid = blockIdx.x;
  const int h = bid & 15, qt = (bid >> 4) & 7, b = bid >> 7;
  const int t = threadIdx.x, w = t >> 6, lane = t & 63, quad = lane >> 4, ln = lane & 15;

  if (t == 0) {   // inline allocation (mirrors jax: round / first-argmax / searchsorted)
    float kn[8];
    for (int kv = 0; kv < 8; ++kv) {
      float s = 0.0f;
      for (int bb = 0; bb < 8; ++bb) s += sqrtf(sums[bb * 8 + kv]);
      kn[kv] = s;
    }
    float mn = kn[0], mx = kn[0];
    for (int i = 1; i < 8; ++i) { mn = fminf(mn, kn[i]); mx = fmaxf(mx, kn[i]); }
    float tot = 0.0f;
    for (int i = 0; i < 8; ++i) { kn[i] = (kn[i] - mn) / (mx - mn); tot += kn[i]; }
    int a[8], sum = 0;
    for (int i = 0; i < 8; ++i) { a[i] = (int)rintf(kn[i] * 16.0f / tot); sum += a[i]; }
    while (sum > 16) {
      int im = 0;
      for (int i = 1; i < 8; ++i) if (a[i] > a[im]) im = i;
      a[im]--; sum--;
    }
    while (sum < 16) {
      int im = 0;
      for (int i = 1; i < 8; ++i) if (a[i] < a[im]) im = i;
      a[im]++; sum++;
    }
    int cum = 0, idx = 0, c[8];
    for (int i = 0; i < 8; ++i) { cum += a[i]; c[i] = cum; }
    while (c[idx] <= h) idx++;
    kvs = idx;
  }
  __syncthreads();
  const int kvi = kvs;

  // Q fragments for both strips (B-operand of S^T): Q[q=ln][d=quad*8+j]
  s16x8 qf[2][2];
  #pragma unroll
  for (int s = 0; s < 2; ++s) {
    const unsigned short* qp = qkv + (long)(b * 1024 + qt * 128 + s * 64 + w * 16 + ln) * 1536
                               + h * 64 + quad * 8;
    qf[s][0] = *(const s16x8*)(qp);
    qf[s][1] = *(const s16x8*)(qp + 32);
  }

  // K staging (gll, XOR chunk swizzle + key permutation pi):
  // Ks row m holds global key kt*64 + pi(m),  pi(m) = m5 | q1 q0 | ks0 | r1 r0.
  const int lc8 = ((lane & 7) ^ (lane >> 3)) << 3;
  const int mA = w * 16 + (lane >> 3);          // LDS rows staged by call A
  const int mB = mA + 8;                        // call B
  const int gA = (mA & 0x20) | ((mA & 0x0C) << 1) | ((mA & 0x10) >> 2) | (mA & 3);
  const int gB = (mB & 0x20) | ((mB & 0x0C) << 1) | ((mB & 0x10) >> 2) | (mB & 3);
  const unsigned short* kglA = qkv + (long)(b * 1024 + gA) * 1536 + 1024 + kvi * 64 + lc8;
  const unsigned short* kglB = qkv + (long)(b * 1024 + gB) * 1536 + 1024 + kvi * 64 + lc8;

  // V^T staging (gll from vT[512][8192], natural d order, chunk-swizzled
  // source so the LDS-linear dest carries the XOR pattern):
  // Vt row r (=d) holds key chunks c at swizzled position c ^ (r&7).
  const unsigned short* vglA = vT + (long)(kvi * 64 + mA) * 8192 + b * 1024 + lc8;
  const unsigned short* vglB = vglA + 8 * 8192;

  s16x8 ones;
  #pragma unroll
  for (int j = 0; j < 8; ++j) ones[j] = (short)0x3F80;   // bf16 1.0

  f32x4 Oa[2][4] = {};    // O^T frags: lane holds O^T[d=ds*16+quad*4+r][q=ln]
  f32x4 lacc[2] = {};
  const f32x4 fz = {0.0f, 0.0f, 0.0f, 0.0f};   // hoisted C-in zero for S^T

  // ---- prologue: stage tile 0 into buffer 0 ----
#ifdef HAVE_GLL
  gll16(kglA, &Ks[0][w * 1024]);
  gll16(kglB, &Ks[0][w * 1024 + 512]);
  gll16(vglA, &Vt[0][w * 1024]);
  gll16(vglB, &Vt[0][w * 1024 + 512]);
#else
  {
    i32x4 t0 = *(const i32x4*)(kglA);
    i32x4 t1 = *(const i32x4*)(kglB);
    i32x4 t2 = *(const i32x4*)(vglA);
    i32x4 t3 = *(const i32x4*)(vglB);
    *(i32x4*)(&Ks[0][w * 1024 + lane * 8]) = t0;
    *(i32x4*)(&Ks[0][w * 1024 + 512 + lane * 8]) = t1;
    *(i32x4*)(&Vt[0][w * 1024 + lane * 8]) = t2;
    *(i32x4*)(&Vt[0][w * 1024 + 512 + lane * 8]) = t3;
  }
#endif
  __syncthreads();

  for (int kt = 0; kt < 16; ++kt) {
    const int cur = kt & 1, nxt = cur ^ 1;

    // -- 1. next tile's staging (all gll; drains at end-of-iter barrier,
    //       a full tile of compute away) --
    if (kt < 15) {
      const long ko = (long)(kt + 1) * 98304;   // 64 rows * 1536
      const long vo = (kt + 1) * 64;            // 64 keys along vT rows
#ifdef HAVE_GLL
      gll16(kglA + ko, &Ks[nxt][w * 1024]);
      gll16(kglB + ko, &Ks[nxt][w * 1024 + 512]);
      gll16(vglA + vo, &Vt[nxt][w * 1024]);
      gll16(vglB + vo, &Vt[nxt][w * 1024 + 512]);
#else
      i32x4 t0 = *(const i32x4*)(kglA + ko);
      i32x4 t1 = *(const i32x4*)(kglB + ko);
      i32x4 t2 = *(const i32x4*)(vglA + vo);
      i32x4 t3 = *(const i32x4*)(vglB + vo);
      *(i32x4*)(&Ks[nxt][w * 1024 + lane * 8]) = t0;
      *(i32x4*)(&Ks[nxt][w * 1024 + 512 + lane * 8]) = t1;
      *(i32x4*)(&Vt[nxt][w * 1024 + lane * 8]) = t2;
      *(i32x4*)(&Vt[nxt][w * 1024 + 512 + lane * 8]) = t3;
#endif
    }

    // -- 2. K fragments for CURRENT tile (A-operand of S^T) --
    s16x8 kfr[2][4];
    #pragma unroll
    for (int ks = 0; ks < 4; ++ks) {
      const int r0 = (ks * 16 + ln) * 64;
      kfr[0][ks] = *(const s16x8*)(&Ks[cur][r0 + (((quad    ) ^ (ln & 7)) << 3)]);
      kfr[1][ks] = *(const s16x8*)(&Ks[cur][r0 + (((quad + 4) ^ (ln & 7)) << 3)]);
    }

    // -- 3. S^T per strip, then pack P directly into PV B-fragments (no LDS)
    // sacc[ks][r] = S^T[slot 32*(ks>>1)+8*quad+4*(ks&1)+r][q=ln]  (via pi)
    // pf[kc] element j = P[slot kc*32+quad*8+j][q=ln]
    s16x8 pfs[2][2];
    #pragma unroll
    for (int s = 0; s < 2; ++s) {
      f32x4 sacc[4];
      __builtin_amdgcn_s_setprio(1);
      #pragma unroll
      for (int ks = 0; ks < 4; ++ks) {
        sacc[ks] = __builtin_amdgcn_mfma_f32_16x16x32_bf16(kfr[0][ks], qf[s][0], fz, 0, 0, 0);
        sacc[ks] = __builtin_amdgcn_mfma_f32_16x16x32_bf16(kfr[1][ks], qf[s][1], sacc[ks], 0, 0, 0);
      }
      __builtin_amdgcn_s_setprio(0);
      #pragma unroll
      for (int kc = 0; kc < 2; ++kc) {
        i32x4 pd;
        pd[0] = (int)pk_bf16(fast_exp2(sacc[2*kc][0]),   fast_exp2(sacc[2*kc][1]));
        pd[1] = (int)pk_bf16(fast_exp2(sacc[2*kc][2]),   fast_exp2(sacc[2*kc][3]));
        pd[2] = (int)pk_bf16(fast_exp2(sacc[2*kc+1][0]), fast_exp2(sacc[2*kc+1][1]));
        pd[3] = (int)pk_bf16(fast_exp2(sacc[2*kc+1][2]), fast_exp2(sacc[2*kc+1][3]));
        pfs[s][kc] = __builtin_bit_cast(s16x8, pd);
      }
    }

    // -- 4. PV + l:  O^T[d][q] += V^T[d][slot] * P[slot][q];  A from Vt[cur].
    //       vf read: row r = ds*16+ln, key chunk (kc*4+quad) at swizzled
    //       position (kc*4+quad) ^ (ln&7)  (matches the staged source swz).
    __builtin_amdgcn_s_setprio(1);
    #pragma unroll
    for (int kc = 0; kc < 2; ++kc) {
      #pragma unroll
      for (int ds = 0; ds < 4; ++ds) {
        s16x8 vf = *(const s16x8*)(&Vt[cur][(ds * 16 + ln) * 64 +
                                            (((kc * 4 + quad) ^ (ln & 7)) << 3)]);
        Oa[0][ds] = __builtin_amdgcn_mfma_f32_16x16x32_bf16(vf, pfs[0][kc], Oa[0][ds], 0, 0, 0);
        Oa[1][ds] = __builtin_amdgcn_mfma_f32_16x16x32_bf16(vf, pfs[1][kc], Oa[1][ds], 0, 0, 0);
      }
      lacc[0] = __builtin_amdgcn_mfma_f32_16x16x32_bf16(ones, pfs[0][kc], lacc[0], 0, 0, 0);
      lacc[1] = __builtin_amdgcn_mfma_f32_16x16x32_bf16(ones, pfs[1][kc], lacc[1], 0, 0, 0);
    }
    __builtin_amdgcn_s_setprio(0);

    __syncthreads();   // single barrier/tile: publishes [nxt], retires [cur]
  }

  // finalize: O^T / l.  lacc rows all equal l[q=ln] -> ONE rcp per lane/strip.
  // Store: lane holds 4 consecutive d per ds -> one 8B store each.
  #pragma unroll
  for (int s = 0; s < 2; ++s) {
    const float inv = 1.0f / lacc[s][0];
    unsigned short* orow = att + (long)(b * 1024 + qt * 128 + s * 64 + w * 16 + ln) * 1024
                           + h * 64 + quad * 4;
    #pragma unroll
    for (int ds = 0; ds < 4; ++ds) {
      i32x2 pk;
      pk[0] = (int)pk_bf16(Oa[s][ds][0] * inv, Oa[s][ds][1] * inv);
      pk[1] = (int)pk_bf16(Oa[s][ds][2] * inv, Oa[s][ds][3] * inv);
      *(i32x2*)(orow + ds * 16) = pk;
    }
  }
}

// ---------------------------------------------------------------------------
// Workspace layout (bytes):
//   xb    @ 0          16,777,216   (bf16 8192x1024)  -- reused as att
//   wqkv  @ 16,777,216  4,194,304   (bf16 2048x1024: Wq*0.125*log2e | Wk | Wv)
//   wpb   @ 20,971,520  2,097,152   (bf16 1024x1024)
//   qkv   @ 23,068,672 25,165,824   (bf16 8192x1536: Q | K)
//   vT    @ 48,234,496  8,388,608   (bf16 512x8192: V^T, d-major)
//   sums  @ 56,623,104        256   (fp32 64: ||K||^2 per (b,kv))
// ---------------------------------------------------------------------------
extern "C" void kernel_launch(void* const* d_in, const int* in_sizes, int n_in,
                              void* d_out, int out_size, void* d_ws, size_t ws_size,
                              hipStream_t stream) {
  const float* x  = (const float*)d_in[0];
  const float* Wq = (const float*)d_in[1];
  const float* Wk = (const float*)d_in[2];
  const float* Wv = (const float*)d_in[3];
  const float* Wp = (const float*)d_in[4];
  const float* bp = (const float*)d_in[5];

  char* ws = (char*)d_ws;
  unsigned short* xb   = (unsigned short*)(ws);
  unsigned short* wqkv = (unsigned short*)(ws + 16777216);
  unsigned short* wpb  = (unsigned short*)(ws + 20971520);
  unsigned short* qkv  = (unsigned short*)(ws + 23068672);
  unsigned short* vT   = (unsigned short*)(ws + 48234496);
  float*          sums = (float*)(ws + 56623104);
  unsigned short* att  = xb;   // xb dead after gemm1

  convert_kernel<<<11264, 256, 0, stream>>>(x, Wq, Wk, Wv, Wp, xb, wqkv, wpb, sums);
  gemm_bt<2048, 1536, true, true><<<1024, 256, 0, stream>>>(xb, wqkv, qkv, nullptr, nullptr, sums, vT);
  attn_kernel<<<1024, 256, 0, stream>>>(qkv, vT, sums, att);
  gemm_bt<1024, 1024, false, false><<<512, 256, 0, stream>>>(att, wpb, nullptr, (float*)d_out, bp, nullptr, nullptr);
}

// Round 6
// 210.707 us; speedup vs baseline: 1.7057x; 1.0019x over previous
//
#include <hip/hip_runtime.h>
#include <stdint.h>

// ---------------------------------------------------------------------------
// KDGQA: x -> (Q,K,V) proj -> dynamic KV allocation from ||K||_F -> grouped
// attention -> output proj + bias.  B=8, P=1024, DIM=1024, H=16, KV=8, HD=64.
// R14: gemm2 pipeline.  gemm2 (M=8192,N=1024) has 512 blocks = 2 blk/CU --
// the m97 2-barrier structure's vmcnt(0)-drain stall is only hidden by
// co-resident blocks, so gemm2 pays it fully.  New: T3-minimal 2-phase
// double-buffer for gemm2 (issue next K-tile's gll BEFORE compute, single
// barrier per step).  LDS 32->64KB is free here: grid already caps at
// 2 blk/CU (2x64KB=128KB<=160KB) -- no occupancy price, pure pipelining
// (same mechanism that took attn 80.9->64us in R10).
// gemm1 unchanged (4 blk/CU grid: dbuf would halve residency -- m132 trap).
// attn unchanged from R13 (57us, 0 bank conflicts).
// ---------------------------------------------------------------------------

typedef float f32x4 __attribute__((ext_vector_type(4)));
typedef int   i32x2 __attribute__((ext_vector_type(2)));
typedef short s16x8 __attribute__((ext_vector_type(8)));
typedef short s16x4 __attribute__((ext_vector_type(4)));
typedef int   i32x4 __attribute__((ext_vector_type(4)));

__device__ __forceinline__ unsigned short f2bf(float f) {
  unsigned int u = __builtin_bit_cast(unsigned int, f);
  u = (u + 0x7FFFu + ((u >> 16) & 1u)) >> 16;   // round-to-nearest-even
  return (unsigned short)u;
}

// packed fp32x2 -> bf16x2 (low = a, high = b)
__device__ __forceinline__ unsigned int pk_bf16(float a, float b) {
#if __has_builtin(__builtin_amdgcn_cvt_pk_bf16_f32)
  auto v = __builtin_amdgcn_cvt_pk_bf16_f32(a, b);
  return __builtin_bit_cast(unsigned int, v);
#else
  unsigned int ua = __builtin_bit_cast(unsigned int, a);
  unsigned int ub = __builtin_bit_cast(unsigned int, b);
  ua += 0x7FFFu + ((ua >> 16) & 1u);
  ub += 0x7FFFu + ((ub >> 16) & 1u);
#if __has_builtin(__builtin_amdgcn_perm)
  return __builtin_amdgcn_perm(ub, ua, 0x07060302);
#else
  return (ua >> 16) | (ub & 0xFFFF0000u);
#endif
#endif
}

__device__ __forceinline__ float fast_exp2(float x) {
#if __has_builtin(__builtin_amdgcn_exp2f)
  return __builtin_amdgcn_exp2f(x);
#else
  return exp2f(x);
#endif
}

#if __has_builtin(__builtin_amdgcn_global_load_lds)
#define HAVE_GLL 1
typedef const __attribute__((address_space(1))) void* gas_ptr;
typedef __attribute__((address_space(3))) void* las_ptr;
__device__ __forceinline__ void gll16(const void* g, void* l) {
  __builtin_amdgcn_global_load_lds((gas_ptr)g, (las_ptr)l, 16, 0, 0);
}
#endif

// ---------------------------------------------------------------------------
// 1. fp32 -> bf16 conversion. Wq gets 0.125 (HD^-0.5) * log2(e) folded in so
//    attention softmax is a raw exp2.  Block 0 also zeroes the sumsq cells.
// ---------------------------------------------------------------------------
__global__ void convert_kernel(const float* __restrict__ x, const float* __restrict__ Wq,
                               const float* __restrict__ Wk, const float* __restrict__ Wv,
                               const float* __restrict__ Wp,
                               unsigned short* __restrict__ xb,
                               unsigned short* __restrict__ wqkv,
                               unsigned short* __restrict__ wpb,
                               float* __restrict__ sums) {
  if (blockIdx.x == 0 && threadIdx.x < 64) sums[threadIdx.x] = 0.0f;
  const long i = ((long)blockIdx.x * 256 + threadIdx.x) * 4;
  const float* src; unsigned short* dst; long off; float scale = 1.0f;
  if (i < 8388608L)       { src = x;  dst = xb;             off = i;             }
  else if (i < 9437184L)  { src = Wq; dst = wqkv;           off = i - 8388608L;  scale = 0.18033688011112042f; }
  else if (i < 9961472L)  { src = Wk; dst = wqkv + 1048576; off = i - 9437184L;  }
  else if (i < 10485760L) { src = Wv; dst = wqkv + 1572864; off = i - 9961472L;  }
  else                    { src = Wp; dst = wpb;            off = i - 10485760L; }
  f32x4 v = *(const f32x4*)(src + off);
  s16x4 o;
  o[0] = (short)f2bf(v[0] * scale);
  o[1] = (short)f2bf(v[1] * scale);
  o[2] = (short)f2bf(v[2] * scale);
  o[3] = (short)f2bf(v[3] * scale);
  *(s16x4*)(dst + off) = o;
}

// ---------------------------------------------------------------------------
// 2. GEMM  C[M][N] = A[M][1024] * B[N][1024]^T, 128x128 tile, BK=64, m97-style
//    global_load_lds staging with XOR chunk swizzle.  DO_SUMSQ: K-range blocks
//    reduce sum(acc^2) per (b, kv head) into sums[] via one atomic per wave.
//    V-region blocks (gemm1, n0>=1536) swap staging pointers so acc holds
//    C^T; epilogue writes vT[512][8192] coalesced.
//    R14: DBUF variant -- 2-phase double-buffered K-loop (issue next tile's
//    gll before compute, one barrier/step) for grid-limited-occupancy gemms.
// ---------------------------------------------------------------------------
template<int N, int OSTR, bool OUT_BF16, bool DO_SUMSQ, bool DBUF>
__global__ __launch_bounds__(256)
void gemm_bt(const unsigned short* __restrict__ A,
             const unsigned short* __restrict__ Bw,
             unsigned short* __restrict__ Cb,
             float* __restrict__ Cf,
             const float* __restrict__ bias,
             float* __restrict__ sums,
             unsigned short* __restrict__ vt) {
  constexpr int NBUF = DBUF ? 2 : 1;
  __shared__ __align__(16) unsigned short As[NBUF][8192];   // 128 rows x 64 shorts
  __shared__ __align__(16) unsigned short Bs[NBUF][8192];
  constexpr int NB = N / 128;
  const int bm = blockIdx.x / NB, bn = blockIdx.x % NB;
  const int m0 = bm * 128, n0 = bn * 128;
  const int t = threadIdx.x;
  const int w = t >> 6, lane = t & 63, quad = lane >> 4, ln = lane & 15;
  const int wm = w & 1, wn = w >> 1;

  // V-region blocks: swap operands so the MFMA produces C^T (n-side on the
  // A-operand).  Block-uniform; MFMA loop below is identical either way.
  const bool vblk = OUT_BF16 && (vt != nullptr) && (n0 >= 1536);
  const unsigned short* Abase = vblk ? Bw : A;
  const unsigned short* Bbase = vblk ? A  : Bw;
  const int ar0 = vblk ? n0 : m0;
  const int br0 = vblk ? m0 : n0;

  const int lrow = lane >> 3;                       // 0..7
  const int lc8  = ((lane & 7) ^ lrow) << 3;        // logical chunk offset (shorts)
  const unsigned short* agl = Abase + (ar0 + w * 32 + lrow) * 1024 + lc8;
  const unsigned short* bgl = Bbase + (br0 + w * 32 + lrow) * 1024 + lc8;

  f32x4 acc[4][4] = {};

  auto stage = [&](int buf, int k0) {
#ifdef HAVE_GLL
    #pragma unroll
    for (int c = 0; c < 4; ++c) {
      gll16(agl + k0 + c * 8192, &As[buf][w * 2048 + c * 512]);
      gll16(bgl + k0 + c * 8192, &Bs[buf][w * 2048 + c * 512]);
    }
#else
    i32x4 ra[4], rb[4];
    #pragma unroll
    for (int c = 0; c < 4; ++c) {
      ra[c] = *(const i32x4*)(agl + k0 + c * 8192);
      rb[c] = *(const i32x4*)(bgl + k0 + c * 8192);
    }
    #pragma unroll
    for (int c = 0; c < 4; ++c) {
      *(i32x4*)(&As[buf][w * 2048 + c * 512 + lane * 8]) = ra[c];
      *(i32x4*)(&Bs[buf][w * 2048 + c * 512 + lane * 8]) = rb[c];
    }
#endif
  };

  auto compute = [&](int buf) {
    #pragma unroll
    for (int kc = 0; kc < 2; ++kc) {
      const int pcs = ((kc * 4 + quad) ^ (ln & 7)) << 3;
      s16x8 af[4], bfr[4];
      #pragma unroll
      for (int i = 0; i < 4; ++i)
        af[i] = *(const s16x8*)(&As[buf][(wm * 64 + i * 16 + ln) * 64 + pcs]);
      #pragma unroll
      for (int j = 0; j < 4; ++j)
        bfr[j] = *(const s16x8*)(&Bs[buf][(wn * 64 + j * 16 + ln) * 64 + pcs]);
      #pragma unroll
      for (int i = 0; i < 4; ++i)
        #pragma unroll
        for (int j = 0; j < 4; ++j)
          acc[i][j] = __builtin_amdgcn_mfma_f32_16x16x32_bf16(af[i], bfr[j], acc[i][j], 0, 0, 0);
    }
  };

  if constexpr (DBUF) {
    // 2-phase: stage(s+1) issued before compute(s); one barrier per step.
    // The barrier's vmcnt(0) drain lands ~a full K-step of compute after the
    // gll issue -> staging latency hidden even at 2 blocks/CU.
    stage(0, 0);
    __syncthreads();
    for (int s = 0; s < 16; ++s) {
      const int cur = s & 1, nxt = cur ^ 1;
      if (s < 15) stage(nxt, (s + 1) * 64);
      compute(cur);
      __syncthreads();
    }
  } else {
    for (int k0 = 0; k0 < 1024; k0 += 64) {
      __syncthreads();
      stage(0, k0);
      __syncthreads();
      compute(0);
    }
  }

  if constexpr (DO_SUMSQ) {
    if (bn >= 8 && bn < 12) {
      float ss = 0.0f;
      #pragma unroll
      for (int i = 0; i < 4; ++i)
        #pragma unroll
        for (int j = 0; j < 4; ++j)
          #pragma unroll
          for (int r = 0; r < 4; ++r)
            ss += acc[i][j][r] * acc[i][j][r];
      #pragma unroll
      for (int off = 1; off < 64; off <<= 1) ss += __shfl_xor(ss, off);
      if (lane == 0)
        atomicAdd(&sums[(m0 >> 10) * 8 + (bn - 8) * 2 + wn], ss);
    }
  }

  if (vblk) {
    // acc = C^T tile: row (quad*4+r) = n-offset, col (ln) = m-offset.
    // vT[512][8192]: 16 lanes -> 16 consecutive columns (32B runs per row).
    #pragma unroll
    for (int j = 0; j < 4; ++j) {
      const int vcol = m0 + wn * 64 + j * 16 + ln;
      #pragma unroll
      for (int i = 0; i < 4; ++i) {
        const int vr0 = (n0 - 1536) + wm * 64 + i * 16 + quad * 4;
        #pragma unroll
        for (int r = 0; r < 4; ++r)
          vt[(long)(vr0 + r) * 8192 + vcol] = f2bf(acc[i][j][r]);
      }
    }
    return;
  }

  // Epilogue. C/D layout: row = quad*4+reg, col = lane&15.
  #pragma unroll
  for (int j = 0; j < 4; ++j) {
    const int gn = n0 + wn * 64 + j * 16 + ln;
    float bv = 0.0f;
    if constexpr (!OUT_BF16) bv = bias[gn];
    #pragma unroll
    for (int i = 0; i < 4; ++i) {
      const int gm0 = m0 + wm * 64 + i * 16 + quad * 4;
      #pragma unroll
      for (int r = 0; r < 4; ++r) {
        float v = acc[i][j][r];
        if constexpr (OUT_BF16) Cb[(long)(gm0 + r) * OSTR + gn] = f2bf(v);
        else                    Cf[(long)(gm0 + r) * OSTR + gn] = v + bv;
      }
    }
  }
}

// ---------------------------------------------------------------------------
// 3. Attention. Block = 4 waves x 2 strips x 16 q = 128 queries of one (b,h).
//    S^T form: sacc = mfma(K_frag, Q_frag) -> C-layout [key][q]; keys staged
//    permuted (Ks row m <- global key pi(m)) so exp2(sacc) packs DIRECTLY
//    into the PV B-fragment (P never touches LDS).
//    V^T precomputed by gemm1 -> V staged via gll like K.  Dbuf both, single
//    barrier/tile; all staging is gll so the barrier's vmcnt(0) drain has a
//    full tile of compute cover.  Hoisted-zero C-in for S^T MFMAs.
// ---------------------------------------------------------------------------
__global__ __launch_bounds__(256, 4)
void attn_kernel(const unsigned short* __restrict__ qkv,
                 const unsigned short* __restrict__ vT,
                 const float* __restrict__ sums,
                 unsigned short* __restrict__ att) {
  __shared__ __align__(16) unsigned short Ks[2][4096];   // 64 keys x 64 d, swizzled+permuted
  __shared__ __align__(16) unsigned short Vt[2][4096];   // V^T: 64 d x 64 keys, chunk-swizzled
  __shared__ int kvs;

  const int bid = blockIdx.x;
  const int h = bid & 15, qt = (bid >> 4) & 7, b = bid >> 7;
  const int t = threadIdx.x, w = t >> 6, lane = t & 63, quad = lane >> 4, ln = lane & 15;

  if (t == 0) {   // inline allocation (mirrors jax: round / first-argmax / searchsorted)
    float kn[8];
    for (int kv = 0; kv < 8; ++kv) {
      float s = 0.0f;
      for (int bb = 0; bb < 8; ++bb) s += sqrtf(sums[bb * 8 + kv]);
      kn[kv] = s;
    }
    float mn = kn[0], mx = kn[0];
    for (int i = 1; i < 8; ++i) { mn = fminf(mn, kn[i]); mx = fmaxf(mx, kn[i]); }
    float tot = 0.0f;
    for (int i = 0; i < 8; ++i) { kn[i] = (kn[i] - mn) / (mx - mn); tot += kn[i]; }
    int a[8], sum = 0;
    for (int i = 0; i < 8; ++i) { a[i] = (int)rintf(kn[i] * 16.0f / tot); sum += a[i]; }
    while (sum > 16) {
      int im = 0;
      for (int i = 1; i < 8; ++i) if (a[i] > a[im]) im = i;
      a[im]--; sum--;
    }
    while (sum < 16) {
      int im = 0;
      for (int i = 1; i < 8; ++i) if (a[i] < a[im]) im = i;
      a[im]++; sum++;
    }
    int cum = 0, idx = 0, c[8];
    for (int i = 0; i < 8; ++i) { cum += a[i]; c[i] = cum; }
    while (c[idx] <= h) idx++;
    kvs = idx;
  }
  __syncthreads();
  const int kvi = kvs;

  // Q fragments for both strips (B-operand of S^T): Q[q=ln][d=quad*8+j]
  s16x8 qf[2][2];
  #pragma unroll
  for (int s = 0; s < 2; ++s) {
    const unsigned short* qp = qkv + (long)(b * 1024 + qt * 128 + s * 64 + w * 16 + ln) * 1536
                               + h * 64 + quad * 8;
    qf[s][0] = *(const s16x8*)(qp);
    qf[s][1] = *(const s16x8*)(qp + 32);
  }

  // K staging (gll, XOR chunk swizzle + key permutation pi):
  // Ks row m holds global key kt*64 + pi(m),  pi(m) = m5 | q1 q0 | ks0 | r1 r0.
  const int lc8 = ((lane & 7) ^ (lane >> 3)) << 3;
  const int mA = w * 16 + (lane >> 3);          // LDS rows staged by call A
  const int mB = mA + 8;                        // call B
  const int gA = (mA & 0x20) | ((mA & 0x0C) << 1) | ((mA & 0x10) >> 2) | (mA & 3);
  const int gB = (mB & 0x20) | ((mB & 0x0C) << 1) | ((mB & 0x10) >> 2) | (mB & 3);
  const unsigned short* kglA = qkv + (long)(b * 1024 + gA) * 1536 + 1024 + kvi * 64 + lc8;
  const unsigned short* kglB = qkv + (long)(b * 1024 + gB) * 1536 + 1024 + kvi * 64 + lc8;

  // V^T staging (gll from vT[512][8192], natural d order, chunk-swizzled
  // source so the LDS-linear dest carries the XOR pattern):
  // Vt row r (=d) holds key chunks c at swizzled position c ^ (r&7).
  const unsigned short* vglA = vT + (long)(kvi * 64 + mA) * 8192 + b * 1024 + lc8;
  const unsigned short* vglB = vglA + 8 * 8192;

  s16x8 ones;
  #pragma unroll
  for (int j = 0; j < 8; ++j) ones[j] = (short)0x3F80;   // bf16 1.0

  f32x4 Oa[2][4] = {};    // O^T frags: lane holds O^T[d=ds*16+quad*4+r][q=ln]
  f32x4 lacc[2] = {};
  const f32x4 fz = {0.0f, 0.0f, 0.0f, 0.0f};   // hoisted C-in zero for S^T

  // ---- prologue: stage tile 0 into buffer 0 ----
#ifdef HAVE_GLL
  gll16(kglA, &Ks[0][w * 1024]);
  gll16(kglB, &Ks[0][w * 1024 + 512]);
  gll16(vglA, &Vt[0][w * 1024]);
  gll16(vglB, &Vt[0][w * 1024 + 512]);
#else
  {
    i32x4 t0 = *(const i32x4*)(kglA);
    i32x4 t1 = *(const i32x4*)(kglB);
    i32x4 t2 = *(const i32x4*)(vglA);
    i32x4 t3 = *(const i32x4*)(vglB);
    *(i32x4*)(&Ks[0][w * 1024 + lane * 8]) = t0;
    *(i32x4*)(&Ks[0][w * 1024 + 512 + lane * 8]) = t1;
    *(i32x4*)(&Vt[0][w * 1024 + lane * 8]) = t2;
    *(i32x4*)(&Vt[0][w * 1024 + 512 + lane * 8]) = t3;
  }
#endif
  __syncthreads();

  for (int kt = 0; kt < 16; ++kt) {
    const int cur = kt & 1, nxt = cur ^ 1;

    // -- 1. next tile's staging (all gll; drains at end-of-iter barrier,
    //       a full tile of compute away) --
    if (kt < 15) {
      const long ko = (long)(kt + 1) * 98304;   // 64 rows * 1536
      const long vo = (kt + 1) * 64;            // 64 keys along vT rows
#ifdef HAVE_GLL
      gll16(kglA + ko, &Ks[nxt][w * 1024]);
      gll16(kglB + ko, &Ks[nxt][w * 1024 + 512]);
      gll16(vglA + vo, &Vt[nxt][w * 1024]);
      gll16(vglB + vo, &Vt[nxt][w * 1024 + 512]);
#else
      i32x4 t0 = *(const i32x4*)(kglA + ko);
      i32x4 t1 = *(const i32x4*)(kglB + ko);
      i32x4 t2 = *(const i32x4*)(vglA + vo);
      i32x4 t3 = *(const i32x4*)(vglB + vo);
      *(i32x4*)(&Ks[nxt][w * 1024 + lane * 8]) = t0;
      *(i32x4*)(&Ks[nxt][w * 1024 + 512 + lane * 8]) = t1;
      *(i32x4*)(&Vt[nxt][w * 1024 + lane * 8]) = t2;
      *(i32x4*)(&Vt[nxt][w * 1024 + 512 + lane * 8]) = t3;
#endif
    }

    // -- 2. K fragments for CURRENT tile (A-operand of S^T) --
    s16x8 kfr[2][4];
    #pragma unroll
    for (int ks = 0; ks < 4; ++ks) {
      const int r0 = (ks * 16 + ln) * 64;
      kfr[0][ks] = *(const s16x8*)(&Ks[cur][r0 + (((quad    ) ^ (ln & 7)) << 3)]);
      kfr[1][ks] = *(const s16x8*)(&Ks[cur][r0 + (((quad + 4) ^ (ln & 7)) << 3)]);
    }

    // -- 3. S^T per strip, then pack P directly into PV B-fragments (no LDS)
    // sacc[ks][r] = S^T[slot 32*(ks>>1)+8*quad+4*(ks&1)+r][q=ln]  (via pi)
    // pf[kc] element j = P[slot kc*32+quad*8+j][q=ln]
    s16x8 pfs[2][2];
    #pragma unroll
    for (int s = 0; s < 2; ++s) {
      f32x4 sacc[4];
      __builtin_amdgcn_s_setprio(1);
      #pragma unroll
      for (int ks = 0; ks < 4; ++ks) {
        sacc[ks] = __builtin_amdgcn_mfma_f32_16x16x32_bf16(kfr[0][ks], qf[s][0], fz, 0, 0, 0);
        sacc[ks] = __builtin_amdgcn_mfma_f32_16x16x32_bf16(kfr[1][ks], qf[s][1], sacc[ks], 0, 0, 0);
      }
      __builtin_amdgcn_s_setprio(0);
      #pragma unroll
      for (int kc = 0; kc < 2; ++kc) {
        i32x4 pd;
        pd[0] = (int)pk_bf16(fast_exp2(sacc[2*kc][0]),   fast_exp2(sacc[2*kc][1]));
        pd[1] = (int)pk_bf16(fast_exp2(sacc[2*kc][2]),   fast_exp2(sacc[2*kc][3]));
        pd[2] = (int)pk_bf16(fast_exp2(sacc[2*kc+1][0]), fast_exp2(sacc[2*kc+1][1]));
        pd[3] = (int)pk_bf16(fast_exp2(sacc[2*kc+1][2]), fast_exp2(sacc[2*kc+1][3]));
        pfs[s][kc] = __builtin_bit_cast(s16x8, pd);
      }
    }

    // -- 4. PV + l:  O^T[d][q] += V^T[d][slot] * P[slot][q];  A from Vt[cur].
    //       vf read: row r = ds*16+ln, key chunk (kc*4+quad) at swizzled
    //       position (kc*4+quad) ^ (ln&7)  (matches the staged source swz).
    __builtin_amdgcn_s_setprio(1);
    #pragma unroll
    for (int kc = 0; kc < 2; ++kc) {
      #pragma unroll
      for (int ds = 0; ds < 4; ++ds) {
        s16x8 vf = *(const s16x8*)(&Vt[cur][(ds * 16 + ln) * 64 +
                                            (((kc * 4 + quad) ^ (ln & 7)) << 3)]);
        Oa[0][ds] = __builtin_amdgcn_mfma_f32_16x16x32_bf16(vf, pfs[0][kc], Oa[0][ds], 0, 0, 0);
        Oa[1][ds] = __builtin_amdgcn_mfma_f32_16x16x32_bf16(vf, pfs[1][kc], Oa[1][ds], 0, 0, 0);
      }
      lacc[0] = __builtin_amdgcn_mfma_f32_16x16x32_bf16(ones, pfs[0][kc], lacc[0], 0, 0, 0);
      lacc[1] = __builtin_amdgcn_mfma_f32_16x16x32_bf16(ones, pfs[1][kc], lacc[1], 0, 0, 0);
    }
    __builtin_amdgcn_s_setprio(0);

    __syncthreads();   // single barrier/tile: publishes [nxt], retires [cur]
  }

  // finalize: O^T / l.  lacc rows all equal l[q=ln] -> ONE rcp per lane/strip.
  // Store: lane holds 4 consecutive d per ds -> one 8B store each.
  #pragma unroll
  for (int s = 0; s < 2; ++s) {
    const float inv = 1.0f / lacc[s][0];
    unsigned short* orow = att + (long)(b * 1024 + qt * 128 + s * 64 + w * 16 + ln) * 1024
                           + h * 64 + quad * 4;
    #pragma unroll
    for (int ds = 0; ds < 4; ++ds) {
      i32x2 pk;
      pk[0] = (int)pk_bf16(Oa[s][ds][0] * inv, Oa[s][ds][1] * inv);
      pk[1] = (int)pk_bf16(Oa[s][ds][2] * inv, Oa[s][ds][3] * inv);
      *(i32x2*)(orow + ds * 16) = pk;
    }
  }
}

// ---------------------------------------------------------------------------
// Workspace layout (bytes):
//   xb    @ 0          16,777,216   (bf16 8192x1024)  -- reused as att
//   wqkv  @ 16,777,216  4,194,304   (bf16 2048x1024: Wq*0.125*log2e | Wk | Wv)
//   wpb   @ 20,971,520  2,097,152   (bf16 1024x1024)
//   qkv   @ 23,068,672 25,165,824   (bf16 8192x1536: Q | K)
//   vT    @ 48,234,496  8,388,608   (bf16 512x8192: V^T, d-major)
//   sums  @ 56,623,104        256   (fp32 64: ||K||^2 per (b,kv))
// ---------------------------------------------------------------------------
extern "C" void kernel_launch(void* const* d_in, const int* in_sizes, int n_in,
                              void* d_out, int out_size, void* d_ws, size_t ws_size,
                              hipStream_t stream) {
  const float* x  = (const float*)d_in[0];
  const float* Wq = (const float*)d_in[1];
  const float* Wk = (const float*)d_in[2];
  const float* Wv = (const float*)d_in[3];
  const float* Wp = (const float*)d_in[4];
  const float* bp = (const float*)d_in[5];

  char* ws = (char*)d_ws;
  unsigned short* xb   = (unsigned short*)(ws);
  unsigned short* wqkv = (unsigned short*)(ws + 16777216);
  unsigned short* wpb  = (unsigned short*)(ws + 20971520);
  unsigned short* qkv  = (unsigned short*)(ws + 23068672);
  unsigned short* vT   = (unsigned short*)(ws + 48234496);
  float*          sums = (float*)(ws + 56623104);
  unsigned short* att  = xb;   // xb dead after gemm1

  convert_kernel<<<11264, 256, 0, stream>>>(x, Wq, Wk, Wv, Wp, xb, wqkv, wpb, sums);
  gemm_bt<2048, 1536, true, true, false><<<1024, 256, 0, stream>>>(xb, wqkv, qkv, nullptr, nullptr, sums, vT);
  attn_kernel<<<1024, 256, 0, stream>>>(qkv, vT, sums, att);
  gemm_bt<1024, 1024, false, false, true><<<512, 256, 0, stream>>>(att, wpb, nullptr, (float*)d_out, bp, nullptr, nullptr);
}